// Round 1
// baseline (425.913 us; speedup 1.0000x reference)
//
#include <hip/hip_runtime.h>
#include <hip/hip_bf16.h>
#include <stdint.h>

typedef __attribute__((ext_vector_type(8))) short s16x8;
typedef __attribute__((ext_vector_type(4))) float f32x4;

#define THRESH 0.3f
#define Mdim 8192
#define Kdim 2048
#define Ndim 8192

#define BM 128
#define BN 128
#define BK 64

static __device__ __forceinline__ unsigned short f2bf(float f) {
  __hip_bfloat16 h = __float2bfloat16(f);
  return __builtin_bit_cast(unsigned short, h);
}

// ---- Pass 1a: x fp32 -> bf16 (vectorized) ----
__global__ void cvt_x_kernel(const float* __restrict__ x,
                             unsigned short* __restrict__ xb, long n4) {
  long i = (long)blockIdx.x * blockDim.x + threadIdx.x;
  long stride = (long)gridDim.x * blockDim.x;
  for (; i < n4; i += stride) {
    float4 v = reinterpret_cast<const float4*>(x)[i];
    ushort4 o;
    o.x = f2bf(v.x); o.y = f2bf(v.y); o.z = f2bf(v.z); o.w = f2bf(v.w);
    reinterpret_cast<ushort4*>(xb)[i] = o;
  }
}

// ---- Pass 1b: w [K][N] fp32 -> ternary bf16 transposed [N][K] ----
// ternary: sign(w) * (|w| > 0.3) ; +1=0x3F80, -1=0xBF80, 0=0 (exact in bf16)
__global__ void tern_tr_kernel(const float* __restrict__ w,
                               unsigned short* __restrict__ bt) {
  __shared__ unsigned short tile[32][33];  // +1 pad: no bank conflicts
  int n0 = blockIdx.x * 32, k0 = blockIdx.y * 32;
  int tx = threadIdx.x, ty = threadIdx.y;  // (32, 8)
  #pragma unroll
  for (int j = 0; j < 4; ++j) {
    int k = k0 + ty + j * 8;
    float v = w[(long)k * Ndim + n0 + tx];
    unsigned short t = (fabsf(v) > THRESH) ? (v > 0.f ? 0x3F80u : 0xBF80u) : 0u;
    tile[ty + j * 8][tx] = t;
  }
  __syncthreads();
  #pragma unroll
  for (int j = 0; j < 4; ++j) {
    int n = n0 + ty + j * 8;
    bt[(long)n * Kdim + k0 + tx] = tile[tx][ty + j * 8];
  }
}

// ---- Pass 2: bf16 MFMA GEMM, C = A[M][K] * Bt[N][K]^T ----
// m97 structure: 128x128 tile, BK=64, 4 waves (2x2), global_load_lds width 16.
__global__ void __launch_bounds__(256) gemm_kernel(
    const unsigned short* __restrict__ A,   // [8192][2048] bf16
    const unsigned short* __restrict__ Bt,  // [8192][2048] bf16 (N-major)
    float* __restrict__ C) {                // [8192][8192] fp32
  __shared__ unsigned short Als[BM][BK];  // 16 KB
  __shared__ unsigned short Bls[BN][BK];  // 16 KB

  int bid = blockIdx.x;
  // XCD-aware swizzle: nwg = 4096, divisible by 8 -> bijective
  int wg = (bid & 7) * 512 + (bid >> 3);
  int tm = wg >> 6, tn = wg & 63;
  long arow0 = (long)tm * BM;
  long brow0 = (long)tn * BN;

  int tid = threadIdx.x;
  int lane = tid & 63;
  int wid = tid >> 6;
  int wr = wid >> 1, wc = wid & 1;  // 2x2 waves, each owns 64x64 output

  int lr = lane & 15;  // fragment row (A) / col (B) within 16
  int lk = lane >> 4;  // k-subgroup 0..3 (8 consecutive k each)

  f32x4 acc[4][4] = {};

  for (int kt = 0; kt < Kdim; kt += BK) {
    __syncthreads();  // previous tile's ds_reads done before overwrite
    #pragma unroll
    for (int i = 0; i < 4; ++i) {
      int fb = i * 256 + wid * 64;    // wave-uniform 16B-chunk base
      int flat = fb + lane;           // this lane's 16B chunk (0..1023)
      int row = flat >> 3, ch = flat & 7;
      const unsigned short* ga = A + (arow0 + row) * Kdim + kt + ch * 8;
      __builtin_amdgcn_global_load_lds(
          (const __attribute__((address_space(1))) void*)ga,
          (__attribute__((address_space(3))) void*)(&Als[0][0] + (size_t)fb * 8),
          16, 0, 0);
      const unsigned short* gb = Bt + (brow0 + row) * Kdim + kt + ch * 8;
      __builtin_amdgcn_global_load_lds(
          (const __attribute__((address_space(1))) void*)gb,
          (__attribute__((address_space(3))) void*)(&Bls[0][0] + (size_t)fb * 8),
          16, 0, 0);
    }
    __syncthreads();  // compiler drains vmcnt(0) before barrier

    #pragma unroll
    for (int ks = 0; ks < BK; ks += 32) {
      int kcol = ks + lk * 8;
      s16x8 af[4], bf[4];
      #pragma unroll
      for (int m = 0; m < 4; ++m)
        af[m] = *reinterpret_cast<const s16x8*>(&Als[wr * 64 + m * 16 + lr][kcol]);
      #pragma unroll
      for (int n = 0; n < 4; ++n)
        bf[n] = *reinterpret_cast<const s16x8*>(&Bls[wc * 64 + n * 16 + lr][kcol]);
      #pragma unroll
      for (int m = 0; m < 4; ++m)
        #pragma unroll
        for (int n = 0; n < 4; ++n)
          acc[m][n] = __builtin_amdgcn_mfma_f32_16x16x32_bf16(
              af[m], bf[n], acc[m][n], 0, 0, 0);
    }
  }

  // epilogue: D row = (lane>>4)*4 + reg, col = lane&15  [m89 verified]
  #pragma unroll
  for (int m = 0; m < 4; ++m) {
    long row0 = arow0 + wr * 64 + m * 16 + lk * 4;
    #pragma unroll
    for (int n = 0; n < 4; ++n) {
      long col = brow0 + wc * 64 + n * 16 + lr;
      #pragma unroll
      for (int r = 0; r < 4; ++r) {
        C[(row0 + r) * Ndim + col] = acc[m][n][r];
      }
    }
  }
}

// ---- fallback if d_ws is too small: simple tiled fp32 GEMM ----
__global__ void fallback_gemm(const float* __restrict__ x,
                              const float* __restrict__ w,
                              float* __restrict__ C) {
  __shared__ float As[16][17];
  __shared__ float Bs[16][17];
  int tx = threadIdx.x, ty = threadIdx.y;
  long row = (long)blockIdx.y * 16 + ty;
  long col = (long)blockIdx.x * 16 + tx;
  float s = 0.f;
  for (int k0 = 0; k0 < Kdim; k0 += 16) {
    As[ty][tx] = x[row * Kdim + k0 + tx];
    float v = w[(long)(k0 + ty) * Ndim + col];
    Bs[ty][tx] = (fabsf(v) > THRESH) ? (v > 0.f ? 1.f : -1.f) : 0.f;
    __syncthreads();
    #pragma unroll
    for (int k = 0; k < 16; ++k) s += As[ty][k] * Bs[k][tx];
    __syncthreads();
  }
  C[row * Ndim + col] = s;
}

extern "C" void kernel_launch(void* const* d_in, const int* in_sizes, int n_in,
                              void* d_out, int out_size, void* d_ws, size_t ws_size,
                              hipStream_t stream) {
  const float* x = (const float*)d_in[0];
  const float* w = (const float*)d_in[1];
  float* out = (float*)d_out;

  size_t abytes = (size_t)Mdim * Kdim * 2;  // 32 MB
  size_t bbytes = (size_t)Ndim * Kdim * 2;  // 32 MB

  if (ws_size >= abytes + bbytes) {
    unsigned short* xb = (unsigned short*)d_ws;
    unsigned short* bt = (unsigned short*)((char*)d_ws + abytes);
    cvt_x_kernel<<<4096, 256, 0, stream>>>(x, xb, (long)Mdim * Kdim / 4);
    tern_tr_kernel<<<dim3(Ndim / 32, Kdim / 32), dim3(32, 8), 0, stream>>>(w, bt);
    gemm_kernel<<<4096, 256, 0, stream>>>(xb, bt, out);
  } else {
    fallback_gemm<<<dim3(Ndim / 16, Mdim / 16), dim3(16, 16), 0, stream>>>(x, w, out);
  }
}

// Round 3
// 277.248 us; speedup vs baseline: 1.5362x; 1.5362x over previous
//
#include <hip/hip_runtime.h>
#include <hip/hip_bf16.h>
#include <stdint.h>

typedef __attribute__((ext_vector_type(8))) short s16x8;
typedef __attribute__((ext_vector_type(4))) float f32x4;

#define THRESH 0.3f
#define Mdim 8192
#define Kdim 2048
#define Ndim 8192
#define NT 32   // K-tiles of 64
#define NIT 16  // 2 K-tiles per iteration

static __device__ __forceinline__ unsigned short f2bf(float f) {
  __hip_bfloat16 h = __float2bfloat16(f);
  return __builtin_bit_cast(unsigned short, h);
}

// ---- Pass 1a: x fp32 -> bf16 (vectorized) ----
__global__ void cvt_x_kernel(const float* __restrict__ x,
                             unsigned short* __restrict__ xb, long n4) {
  long i = (long)blockIdx.x * blockDim.x + threadIdx.x;
  long stride = (long)gridDim.x * blockDim.x;
  for (; i < n4; i += stride) {
    float4 v = reinterpret_cast<const float4*>(x)[i];
    ushort4 o;
    o.x = f2bf(v.x); o.y = f2bf(v.y); o.z = f2bf(v.z); o.w = f2bf(v.w);
    reinterpret_cast<ushort4*>(xb)[i] = o;
  }
}

// ---- Pass 1b: w [K][N] fp32 -> ternary bf16 transposed [N][K] ----
__global__ void tern_tr_kernel(const float* __restrict__ w,
                               unsigned short* __restrict__ bt) {
  __shared__ unsigned short tile[32][33];
  int n0 = blockIdx.x * 32, k0 = blockIdx.y * 32;
  int tx = threadIdx.x, ty = threadIdx.y;  // (32, 8)
  #pragma unroll
  for (int j = 0; j < 4; ++j) {
    int k = k0 + ty + j * 8;
    float v = w[(long)k * Ndim + n0 + tx];
    unsigned short t = (fabsf(v) > THRESH) ? (v > 0.f ? 0x3F80u : 0xBF80u) : 0u;
    tile[ty + j * 8][tx] = t;
  }
  __syncthreads();
  #pragma unroll
  for (int j = 0; j < 4; ++j) {
    int n = n0 + ty + j * 8;
    bt[(long)n * Kdim + k0 + tx] = tile[tx][ty + j * 8];
  }
}

// ---- Pass 2: 256x256 8-phase bf16 MFMA GEMM, C = A * Bt^T ----
// 8 waves (2M x 4N), BK=64, double-buffered 128 KiB LDS, XOR-swizzled reads,
// pre-swizzled global_load_lds sources, counted vmcnt, setprio around MFMA.
__global__ void __launch_bounds__(512, 1) gemm8_kernel(
    const unsigned short* __restrict__ A,   // [8192][2048] bf16
    const unsigned short* __restrict__ Bt,  // [8192][2048] bf16 (N-major)
    float* __restrict__ C) {                // [8192][8192] fp32
  // layout: buf p at p*65536; A-tile at +0 (256 rows x 128B), B-tile at +32768
  __shared__ __align__(128) char lds[131072];

  int bid = blockIdx.x;
  // XCD swizzle: 1024 blocks, divisible by 8 -> bijective
  int wg = (bid & 7) * 128 + (bid >> 3);
  int tm = wg >> 5, tn = wg & 31;
  long arow0 = (long)tm * 256;
  long bcol0 = (long)tn * 256;

  int tid = threadIdx.x;
  int lane = tid & 63, wid = tid >> 6;
  int wr = wid >> 2, wc = wid & 3;  // 2M x 4N waves; per-wave C = 128x64
  int lr = lane & 15, lk = lane >> 4;

  // stage one half-tile (128 rows x 64 cols bf16 = 16KB) of tile u.
  // which: 0=A, 1=B. Linear LDS dest; INVERSE-swizzled global source so the
  // swizzled reader sees the right data (rule: both-sides-or-neither).
  auto stage = [&](int u, int which, int h) {
    if (u >= NT) return;
    int p = u & 1;
    const unsigned short* gsrc = which ? Bt : A;
    long grow0 = which ? bcol0 : arow0;
    int base = p * 65536 + which * 32768 + h * 16384;
    int kt = u * 64;
    #pragma unroll
    for (int c = 0; c < 2; ++c) {
      int s = c * 512 + tid;          // 16B slot index 0..1023
      int r = h * 128 + (s >> 3);     // tile row
      int co = (s & 7) ^ (r & 7);     // original 16B chunk within the row
      const unsigned short* g = gsrc + (grow0 + r) * (long)Kdim + kt + co * 8;
      __builtin_amdgcn_global_load_lds(
          (const __attribute__((address_space(1))) void*)g,
          (__attribute__((address_space(3))) void*)(lds + base +
                                                   (c * 512 + wid * 64) * 16),
          16, 0, 0);
    }
  };

  // swizzled fragment read: row-major [256][64] bf16, byte ^= (row&7)<<4
  auto frag = [&](int p, int which, int row, int kcol) -> s16x8 {
    int off = p * 65536 + which * 32768 + row * 128 +
              ((((kcol >> 3) ^ (row & 7))) << 4);
    return *reinterpret_cast<const s16x8*>(lds + off);
  };

  f32x4 acc[8][4] = {};
  s16x8 bf[4][2];

  // prologue: tile0 fully, tile1 B-halves; allow t1.B in flight (vmcnt(4))
  stage(0, 1, 0); stage(0, 1, 1); stage(0, 0, 0); stage(0, 0, 1);
  stage(1, 1, 0); stage(1, 1, 1);
  asm volatile("s_waitcnt vmcnt(4)" ::: "memory");
  __builtin_amdgcn_s_barrier();

  for (int it = 0; it < NIT; ++it) {
    int t = 2 * it;
    bool last = (it == NIT - 1);
    #pragma unroll
    for (int half = 0; half < 2; ++half) {
      int p = half;          // tile (t+half) lives in buf[half]
      // stage slots: half0 -> {(t+1).A0,(t+1).A1,(t+2).B0,(t+2).B1}
      //              half1 -> {(t+2).A0,(t+2).A1,(t+3).B0,(t+3).B1}
      int u_a = t + 1 + half;  // A target tile
      int u_b = t + 2 + half;  // B target tile
      #pragma unroll
      for (int q = 0; q < 4; ++q) {
        // ds-load register subtile for this phase
        s16x8 af[2][2];
        #pragma unroll
        for (int m = 0; m < 2; ++m)
          #pragma unroll
          for (int ks = 0; ks < 2; ++ks)
            af[m][ks] = frag(p, 0, wr * 128 + q * 32 + m * 16 + lr,
                             ks * 32 + lk * 8);
        if (q == 0) {
          #pragma unroll
          for (int n = 0; n < 4; ++n)
            #pragma unroll
            for (int ks = 0; ks < 2; ++ks)
              bf[n][ks] = frag(p, 1, wc * 64 + n * 16 + lr, ks * 32 + lk * 8);
        }
        // stage one half-tile prefetch
        if (q == 0) stage(u_a, 0, 0);
        else if (q == 1) stage(u_a, 0, 1);
        else if (q == 2) stage(u_b, 1, 0);
        else stage(u_b, 1, 1);

        if (q == 0) asm volatile("s_waitcnt lgkmcnt(8)" ::: "memory");
        __builtin_amdgcn_s_barrier();
        asm volatile("s_waitcnt lgkmcnt(0)" ::: "memory");
        __builtin_amdgcn_s_setprio(1);
        #pragma unroll
        for (int ks = 0; ks < 2; ++ks)
          #pragma unroll
          for (int m = 0; m < 2; ++m)
            #pragma unroll
            for (int n = 0; n < 4; ++n)
              acc[q * 2 + m][n] = __builtin_amdgcn_mfma_f32_16x16x32_bf16(
                  af[m][ks], bf[n][ks], acc[q * 2 + m][n], 0, 0, 0);
        __builtin_amdgcn_s_setprio(0);
        if (q == 3) {
          // TAIL FIX: when u_b's stages were skipped (final iteration), the
          // 4 in-flight loads vmcnt(4) would exempt are u_a's A-halves --
          // which the NEXT half consumes. Drain fully there instead.
          if (last) asm volatile("s_waitcnt vmcnt(0)" ::: "memory");
          else      asm volatile("s_waitcnt vmcnt(4)" ::: "memory");
        }
        __builtin_amdgcn_s_barrier();
      }
    }
  }

  // epilogue: D row = lk*4 + reg, col = lr within each 16x16 fragment
  #pragma unroll
  for (int m = 0; m < 8; ++m) {
    long row0 = arow0 + wr * 128 + m * 16 + lk * 4;
    #pragma unroll
    for (int n = 0; n < 4; ++n) {
      long col = bcol0 + wc * 64 + n * 16 + lr;
      #pragma unroll
      for (int r = 0; r < 4; ++r)
        C[(row0 + r) * Ndim + col] = acc[m][n][r];
    }
  }
}

// ---- fallback if d_ws is too small: simple tiled fp32 GEMM ----
__global__ void fallback_gemm(const float* __restrict__ x,
                              const float* __restrict__ w,
                              float* __restrict__ C) {
  __shared__ float As[16][17];
  __shared__ float Bs[16][17];
  int tx = threadIdx.x, ty = threadIdx.y;
  long row = (long)blockIdx.y * 16 + ty;
  long col = (long)blockIdx.x * 16 + tx;
  float s = 0.f;
  for (int k0 = 0; k0 < Kdim; k0 += 16) {
    As[ty][tx] = x[row * Kdim + k0 + tx];
    float v = w[(long)(k0 + ty) * Ndim + col];
    Bs[ty][tx] = (fabsf(v) > THRESH) ? (v > 0.f ? 1.f : -1.f) : 0.f;
    __syncthreads();
    #pragma unroll
    for (int k = 0; k < 16; ++k) s += As[ty][k] * Bs[k][tx];
    __syncthreads();
  }
  C[row * Ndim + col] = s;
}

extern "C" void kernel_launch(void* const* d_in, const int* in_sizes, int n_in,
                              void* d_out, int out_size, void* d_ws, size_t ws_size,
                              hipStream_t stream) {
  const float* x = (const float*)d_in[0];
  const float* w = (const float*)d_in[1];
  float* out = (float*)d_out;

  size_t abytes = (size_t)Mdim * Kdim * 2;  // 32 MB
  size_t bbytes = (size_t)Ndim * Kdim * 2;  // 32 MB

  if (ws_size >= abytes + bbytes) {
    unsigned short* xb = (unsigned short*)d_ws;
    unsigned short* bt = (unsigned short*)((char*)d_ws + abytes);
    cvt_x_kernel<<<4096, 256, 0, stream>>>(x, xb, (long)Mdim * Kdim / 4);
    tern_tr_kernel<<<dim3(Ndim / 32, Kdim / 32), dim3(32, 8), 0, stream>>>(w, bt);
    gemm8_kernel<<<1024, 512, 0, stream>>>(xb, bt, out);
  } else {
    fallback_gemm<<<dim3(Ndim / 16, Mdim / 16), dim3(16, 16), 0, stream>>>(x, w, out);
  }
}

// Round 4
// 273.116 us; speedup vs baseline: 1.5595x; 1.0151x over previous
//
#include <hip/hip_runtime.h>
#include <hip/hip_bf16.h>
#include <stdint.h>

typedef __attribute__((ext_vector_type(8))) short s16x8;
typedef __attribute__((ext_vector_type(4))) float f32x4;

#define THRESH 0.3f
#define Mdim 8192
#define Kdim 2048
#define Ndim 8192
#define NT 32   // K-tiles of 64
#define NIT 16  // 2 K-tiles per iteration

static __device__ __forceinline__ unsigned short f2bf(float f) {
  __hip_bfloat16 h = __float2bfloat16(f);
  return __builtin_bit_cast(unsigned short, h);
}

// ---- Pass 1a: x fp32 -> bf16 (vectorized) ----
__global__ void cvt_x_kernel(const float* __restrict__ x,
                             unsigned short* __restrict__ xb, long n4) {
  long i = (long)blockIdx.x * blockDim.x + threadIdx.x;
  long stride = (long)gridDim.x * blockDim.x;
  for (; i < n4; i += stride) {
    float4 v = reinterpret_cast<const float4*>(x)[i];
    ushort4 o;
    o.x = f2bf(v.x); o.y = f2bf(v.y); o.z = f2bf(v.z); o.w = f2bf(v.w);
    reinterpret_cast<ushort4*>(xb)[i] = o;
  }
}

// ---- Pass 1b: w [K][N] fp32 -> ternary bf16 transposed [N][K] ----
__global__ void tern_tr_kernel(const float* __restrict__ w,
                               unsigned short* __restrict__ bt) {
  __shared__ unsigned short tile[32][33];
  int n0 = blockIdx.x * 32, k0 = blockIdx.y * 32;
  int tx = threadIdx.x, ty = threadIdx.y;  // (32, 8)
  #pragma unroll
  for (int j = 0; j < 4; ++j) {
    int k = k0 + ty + j * 8;
    float v = w[(long)k * Ndim + n0 + tx];
    unsigned short t = (fabsf(v) > THRESH) ? (v > 0.f ? 0x3F80u : 0xBF80u) : 0u;
    tile[ty + j * 8][tx] = t;
  }
  __syncthreads();
  #pragma unroll
  for (int j = 0; j < 4; ++j) {
    int n = n0 + ty + j * 8;
    bt[(long)n * Kdim + k0 + tx] = tile[tx][ty + j * 8];
  }
}

// ---- Pass 2: 256x256 8-phase bf16 MFMA GEMM, C = A * Bt^T ----
// 8 waves (2M x 4N), BK=64, double-buffered 128 KiB LDS, XOR-swizzled reads,
// pre-swizzled global_load_lds sources, counted vmcnt, setprio around MFMA.
__global__ void __launch_bounds__(512, 1) gemm8_kernel(
    const unsigned short* __restrict__ A,   // [8192][2048] bf16
    const unsigned short* __restrict__ Bt,  // [8192][2048] bf16 (N-major)
    float* __restrict__ C) {                // [8192][8192] fp32
  // layout: buf p at p*65536; A-tile at +0 (256 rows x 128B), B-tile at +32768
  __shared__ __align__(128) char lds[131072];

  int bid = blockIdx.x;
  // 2D XCD-chunked swizzle (bijective over 32x32 tiles):
  // XCD x owns tm-band [4x, 4x+4) -> its A working set = 4 MB = L2 size.
  // Within the band, enumerate in chunks of 4(tm) x 8(tn): the ~32
  // concurrently-resident blocks per XCD then share 4 A-panels + 8 B-panels
  // (12 MB, cache-resident) instead of 1 A-panel + 32 B-panels (33 MB,
  // which streamed all of B through L2/L3 every block-wave -> 543 MB HBM
  // fetch observed in round 3).
  int x = bid & 7;        // XCD
  int o = bid >> 3;       // 0..127 position within this XCD's sequence
  int c = o >> 5;         // time-chunk 0..3 (tn groups of 8)
  int w = o & 31;         // position within chunk
  int tm = x * 4 + (w >> 3);
  int tn = c * 8 + (w & 7);
  long arow0 = (long)tm * 256;
  long bcol0 = (long)tn * 256;

  int tid = threadIdx.x;
  int lane = tid & 63, wid = tid >> 6;
  int wr = wid >> 2, wc = wid & 3;  // 2M x 4N waves; per-wave C = 128x64
  int lr = lane & 15, lk = lane >> 4;

  // stage one half-tile (128 rows x 64 cols bf16 = 16KB) of tile u.
  // which: 0=A, 1=B. Linear LDS dest; INVERSE-swizzled global source so the
  // swizzled reader sees the right data (rule: both-sides-or-neither).
  auto stage = [&](int u, int which, int h) {
    if (u >= NT) return;
    int p = u & 1;
    const unsigned short* gsrc = which ? Bt : A;
    long grow0 = which ? bcol0 : arow0;
    int base = p * 65536 + which * 32768 + h * 16384;
    int kt = u * 64;
    #pragma unroll
    for (int cc = 0; cc < 2; ++cc) {
      int s = cc * 512 + tid;         // 16B slot index 0..1023
      int r = h * 128 + (s >> 3);     // tile row
      int co = (s & 7) ^ (r & 7);     // original 16B chunk within the row
      const unsigned short* g = gsrc + (grow0 + r) * (long)Kdim + kt + co * 8;
      __builtin_amdgcn_global_load_lds(
          (const __attribute__((address_space(1))) void*)g,
          (__attribute__((address_space(3))) void*)(lds + base +
                                                   (cc * 512 + wid * 64) * 16),
          16, 0, 0);
    }
  };

  // swizzled fragment read: row-major [256][64] bf16, byte ^= (row&7)<<4
  auto frag = [&](int p, int which, int row, int kcol) -> s16x8 {
    int off = p * 65536 + which * 32768 + row * 128 +
              ((((kcol >> 3) ^ (row & 7))) << 4);
    return *reinterpret_cast<const s16x8*>(lds + off);
  };

  f32x4 acc[8][4] = {};
  s16x8 bf[4][2];

  // prologue: tile0 fully, tile1 B-halves; allow t1.B in flight (vmcnt(4))
  stage(0, 1, 0); stage(0, 1, 1); stage(0, 0, 0); stage(0, 0, 1);
  stage(1, 1, 0); stage(1, 1, 1);
  asm volatile("s_waitcnt vmcnt(4)" ::: "memory");
  __builtin_amdgcn_s_barrier();

  for (int it = 0; it < NIT; ++it) {
    int t = 2 * it;
    bool last = (it == NIT - 1);
    #pragma unroll
    for (int half = 0; half < 2; ++half) {
      int p = half;          // tile (t+half) lives in buf[half]
      // stage slots: half0 -> {(t+1).A0,(t+1).A1,(t+2).B0,(t+2).B1}
      //              half1 -> {(t+2).A0,(t+2).A1,(t+3).B0,(t+3).B1}
      int u_a = t + 1 + half;  // A target tile
      int u_b = t + 2 + half;  // B target tile
      #pragma unroll
      for (int q = 0; q < 4; ++q) {
        // ds-load register subtile for this phase
        s16x8 af[2][2];
        #pragma unroll
        for (int m = 0; m < 2; ++m)
          #pragma unroll
          for (int ks = 0; ks < 2; ++ks)
            af[m][ks] = frag(p, 0, wr * 128 + q * 32 + m * 16 + lr,
                             ks * 32 + lk * 8);
        if (q == 0) {
          #pragma unroll
          for (int n = 0; n < 4; ++n)
            #pragma unroll
            for (int ks = 0; ks < 2; ++ks)
              bf[n][ks] = frag(p, 1, wc * 64 + n * 16 + lr, ks * 32 + lk * 8);
        }
        // stage one half-tile prefetch
        if (q == 0) stage(u_a, 0, 0);
        else if (q == 1) stage(u_a, 0, 1);
        else if (q == 2) stage(u_b, 1, 0);
        else stage(u_b, 1, 1);

        if (q == 0) asm volatile("s_waitcnt lgkmcnt(8)" ::: "memory");
        __builtin_amdgcn_s_barrier();
        asm volatile("s_waitcnt lgkmcnt(0)" ::: "memory");
        __builtin_amdgcn_s_setprio(1);
        #pragma unroll
        for (int ks = 0; ks < 2; ++ks)
          #pragma unroll
          for (int m = 0; m < 2; ++m)
            #pragma unroll
            for (int n = 0; n < 4; ++n)
              acc[q * 2 + m][n] = __builtin_amdgcn_mfma_f32_16x16x32_bf16(
                  af[m][ks], bf[n][ks], acc[q * 2 + m][n], 0, 0, 0);
        __builtin_amdgcn_s_setprio(0);
        if (q == 3) {
          // TAIL FIX: when u_b's stages were skipped (final iteration), the
          // 4 in-flight loads vmcnt(4) would exempt are u_a's A-halves --
          // which the NEXT half consumes. Drain fully there instead.
          if (last) asm volatile("s_waitcnt vmcnt(0)" ::: "memory");
          else      asm volatile("s_waitcnt vmcnt(4)" ::: "memory");
        }
        __builtin_amdgcn_s_barrier();
      }
    }
  }

  // epilogue: D row = lk*4 + reg, col = lr within each 16x16 fragment
  #pragma unroll
  for (int m = 0; m < 8; ++m) {
    long row0 = arow0 + wr * 128 + m * 16 + lk * 4;
    #pragma unroll
    for (int n = 0; n < 4; ++n) {
      long col = bcol0 + wc * 64 + n * 16 + lr;
      #pragma unroll
      for (int r = 0; r < 4; ++r)
        C[(row0 + r) * Ndim + col] = acc[m][n][r];
    }
  }
}

// ---- fallback if d_ws is too small: simple tiled fp32 GEMM ----
__global__ void fallback_gemm(const float* __restrict__ x,
                              const float* __restrict__ w,
                              float* __restrict__ C) {
  __shared__ float As[16][17];
  __shared__ float Bs[16][17];
  int tx = threadIdx.x, ty = threadIdx.y;
  long row = (long)blockIdx.y * 16 + ty;
  long col = (long)blockIdx.x * 16 + tx;
  float s = 0.f;
  for (int k0 = 0; k0 < Kdim; k0 += 16) {
    As[ty][tx] = x[row * Kdim + k0 + tx];
    float v = w[(long)(k0 + ty) * Ndim + col];
    Bs[ty][tx] = (fabsf(v) > THRESH) ? (v > 0.f ? 1.f : -1.f) : 0.f;
    __syncthreads();
    #pragma unroll
    for (int k = 0; k < 16; ++k) s += As[ty][k] * Bs[k][tx];
    __syncthreads();
  }
  C[row * Ndim + col] = s;
}

extern "C" void kernel_launch(void* const* d_in, const int* in_sizes, int n_in,
                              void* d_out, int out_size, void* d_ws, size_t ws_size,
                              hipStream_t stream) {
  const float* x = (const float*)d_in[0];
  const float* w = (const float*)d_in[1];
  float* out = (float*)d_out;

  size_t abytes = (size_t)Mdim * Kdim * 2;  // 32 MB
  size_t bbytes = (size_t)Ndim * Kdim * 2;  // 32 MB

  if (ws_size >= abytes + bbytes) {
    unsigned short* xb = (unsigned short*)d_ws;
    unsigned short* bt = (unsigned short*)((char*)d_ws + abytes);
    cvt_x_kernel<<<4096, 256, 0, stream>>>(x, xb, (long)Mdim * Kdim / 4);
    tern_tr_kernel<<<dim3(Ndim / 32, Kdim / 32), dim3(32, 8), 0, stream>>>(w, bt);
    gemm8_kernel<<<1024, 512, 0, stream>>>(xb, bt, out);
  } else {
    fallback_gemm<<<dim3(Ndim / 16, Mdim / 16), dim3(16, 16), 0, stream>>>(x, w, out);
  }
}